// Round 3
// baseline (900.480 us; speedup 1.0000x reference)
//
#include <hip/hip_runtime.h>
#include <hip/hip_bf16.h>

#define N_ENT 100000
#define N_USR 50000
#define DIM   64
#define NE    1000000
#define NNZV  1000000
#define NRELM1 31

__device__ __forceinline__ float bf2f(unsigned short u) {
    return __uint_as_float(((unsigned int)u) << 16);
}
// index fetch: is64 -> data is little-endian int64, take low word
__device__ __forceinline__ int geti(const int* p, size_t i, int is64) {
    return is64 ? p[2 * i] : p[i];
}
// float fetch: isf32 -> data is fp32; else bf16
__device__ __forceinline__ float getf(const void* p, size_t i, int isf32) {
    return isf32 ? ((const float*)p)[i] : bf2f(((const unsigned short*)p)[i]);
}
__device__ __forceinline__ int clampi(int v, int lo, int hi) {
    return v < lo ? lo : (v > hi ? hi : v);
}

// ---------------- Pass 0: dtype detection (deterministic, capture-safe) ----------------
// one wave; lane-parallel probes + ballot
__global__ void detect_kernel(const int* __restrict__ eidx,
                              const unsigned short* __restrict__ ent,
                              int* __restrict__ flags) {
    int lane = threadIdx.x & 63;
    // int64 test: if edge_index is int64, every odd int32 word is 0 (values < 2^17)
    int odd = eidx[2 * lane + 1];
    unsigned long long nz = __ballot(odd != 0);
    // fp32 test: reinterpret first 128 u16 as bf16. Genuine bf16 emb ~N(0,0.1) is
    // moderate; fp32 low-mantissa words have random exponents -> wild values.
    float v0 = fabsf(bf2f(ent[lane]));
    float v1 = fabsf(bf2f(ent[64 + lane]));
    int wild = (int)((v0 > 100.f) || (v0 != 0.f && v0 < 1e-10f)) +
               (int)((v1 > 100.f) || (v1 != 0.f && v1 < 1e-10f));
    #pragma unroll
    for (int off = 32; off >= 1; off >>= 1) wild += __shfl_xor(wild, off, 64);
    if (lane == 0) {
        flags[0] = (nz == 0ULL) ? 1 : 0;   // is64
        flags[1] = (wild >= 16) ? 1 : 0;   // isf32
    }
}

// ---------------- Pass 1: per-edge attention score + segment max ----------------
// one wave (64 lanes) per edge; lane d handles dim d
__global__ __launch_bounds__(256) void edge_att_kernel(
    const void* __restrict__ ent,             // [N_ENT,64]
    const int* __restrict__ eidx,             // [2,NE]
    const int* __restrict__ etype,            // [NE]
    const void* __restrict__ wgt,             // [31,64]
    float* __restrict__ att,                  // [NE]
    float* __restrict__ mseg,                 // [N_ENT], init 0 (att >= 0)
    const int* __restrict__ flags)
{
    int e = (blockIdx.x * blockDim.x + threadIdx.x) >> 6;
    int lane = threadIdx.x & 63;
    if (e >= NE) return;
    int is64 = flags[0], isf32 = flags[1];
    int head = clampi(geti(eidx, e, is64), 0, N_ENT - 1);
    int tail = clampi(geti(eidx, (size_t)NE + e, is64), 0, N_ENT - 1);
    int r    = clampi(geti(etype, e, is64) - 1, 0, NRELM1 - 1);

    float rv = getf(wgt, (size_t)r * DIM + lane, isf32);
    float hv = getf(ent, (size_t)head * DIM + lane, isf32) * rv;
    float tv = getf(ent, (size_t)tail * DIM + lane, isf32) * rv;
    float hh = hv * hv;
    float tt = tv * tv;
    #pragma unroll
    for (int off = 32; off >= 1; off >>= 1) {
        hh += __shfl_xor(hh, off, 64);
        tt += __shfl_xor(tt, off, 64);
    }
    float a = hh * tt;   // == (||h*r|| * ||t*r||)^2, no sqrt needed
    if (lane == 0) {
        att[e] = a;
        atomicMax((unsigned int*)(mseg + head), __float_as_uint(a)); // a >= 0
    }
}

// ---------------- Pass 2: exp(att - m[head]) and segment sum ----------------
__global__ __launch_bounds__(256) void edge_exp_kernel(
    const int* __restrict__ eidx,
    float* __restrict__ attex,     // in: att, out: ex (in place)
    const float* __restrict__ mseg,
    float* __restrict__ sseg,      // [N_ENT], init 0
    const int* __restrict__ flags)
{
    int e = blockIdx.x * blockDim.x + threadIdx.x;
    if (e >= NE) return;
    int is64 = flags[0];
    int head = clampi(geti(eidx, e, is64), 0, N_ENT - 1);
    float ex = __expf(attex[e] - mseg[head]);
    attex[e] = ex;
    atomicAdd(sseg + head, ex);
}

// ---------------- Pass 3: entity aggregation (direct into fp32 d_out) ----------------
// one wave per edge; lane d atomically accumulates dim d
__global__ __launch_bounds__(256) void edge_agg_kernel(
    const void* __restrict__ ent,
    const int* __restrict__ eidx,
    const int* __restrict__ etype,
    const void* __restrict__ wgt,
    const float* __restrict__ ex,
    const float* __restrict__ sseg,
    float* __restrict__ ent_out,   // [N_ENT,64] fp32 = d_out, zeroed
    const int* __restrict__ flags)
{
    int e = (blockIdx.x * blockDim.x + threadIdx.x) >> 6;
    int lane = threadIdx.x & 63;
    if (e >= NE) return;
    int is64 = flags[0], isf32 = flags[1];
    int head = clampi(geti(eidx, e, is64), 0, N_ENT - 1);
    int tail = clampi(geti(eidx, (size_t)NE + e, is64), 0, N_ENT - 1);
    int r    = clampi(geti(etype, e, is64) - 1, 0, NRELM1 - 1);
    float w = ex[e] / sseg[head];
    float nv = getf(ent, (size_t)tail * DIM + lane, isf32) *
               getf(wgt, (size_t)r * DIM + lane, isf32);
    atomicAdd(ent_out + (size_t)head * DIM + lane, w * nv);
}

// ---------------- user_agg spmm (COO, direct into fp32 d_out) ----------------
__global__ __launch_bounds__(256) void spmm_kernel(
    const void* __restrict__ ent,
    const int* __restrict__ irow,
    const int* __restrict__ icol,
    const void* __restrict__ ival,
    float* __restrict__ usr_out,   // [N_USR,64] fp32 = d_out + N_ENT*DIM, zeroed
    const int* __restrict__ flags)
{
    int n = (blockIdx.x * blockDim.x + threadIdx.x) >> 6;
    int lane = threadIdx.x & 63;
    if (n >= NNZV) return;
    int is64 = flags[0], isf32 = flags[1];
    int row = clampi(geti(irow, n, is64), 0, N_USR - 1);
    int col = clampi(geti(icol, n, is64), 0, N_ENT - 1);
    float v = getf(ival, n, isf32);
    float c = getf(ent, (size_t)col * DIM + lane, isf32);
    atomicAdd(usr_out + (size_t)row * DIM + lane, v * c);
}

// ---------------- user finalize: softmax gate, in place on fp32 out ----------------
// one thread per user; weight staged in LDS (fp32)
__global__ __launch_bounds__(256) void user_final_kernel(
    const void* __restrict__ usr,             // [N_USR,64]
    const void* __restrict__ wgt,             // [31,64]
    float* __restrict__ usr_out,              // [N_USR,64] fp32, holds raw user_agg
    const int* __restrict__ flags)
{
    __shared__ float w[NRELM1][DIM];
    int isf32 = flags[1];
    for (int i = threadIdx.x; i < NRELM1 * DIM; i += blockDim.x) {
        ((float*)w)[i] = getf(wgt, i, isf32);
    }
    __syncthreads();
    int u = blockIdx.x * blockDim.x + threadIdx.x;
    if (u >= N_USR) return;

    float ue[DIM];
    #pragma unroll
    for (int d = 0; d < DIM; ++d) ue[d] = getf(usr, (size_t)u * DIM + d, isf32);

    float sc[NRELM1];
    float mx = -1e30f;
    #pragma unroll
    for (int r = 0; r < NRELM1; ++r) {
        float s = 0.f;
        #pragma unroll
        for (int d = 0; d < DIM; ++d) s += ue[d] * w[r][d];
        sc[r] = s;
        mx = fmaxf(mx, s);
    }
    float sum = 0.f;
    #pragma unroll
    for (int r = 0; r < NRELM1; ++r) {
        sc[r] = __expf(sc[r] - mx);
        sum += sc[r];
    }
    float inv = 1.f / sum;
    #pragma unroll
    for (int d = 0; d < DIM; ++d) {
        float v = 0.f;
        #pragma unroll
        for (int r = 0; r < NRELM1; ++r) v += sc[r] * w[r][d];
        v *= inv;
        float ua = usr_out[(size_t)u * DIM + d];
        usr_out[(size_t)u * DIM + d] = ua + v * ua;   // fp32 in place
    }
}

extern "C" void kernel_launch(void* const* d_in, const int* in_sizes, int n_in,
                              void* d_out, int out_size, void* d_ws, size_t ws_size,
                              hipStream_t stream) {
    const void* ent  = d_in[0];
    const void* usr  = d_in[1];
    const int* eidx  = (const int*)d_in[2];
    const int* etype = (const int*)d_in[3];
    const int* irow  = (const int*)d_in[4];
    const int* icol  = (const int*)d_in[5];
    const void* ival = d_in[6];
    const void* wgt  = d_in[7];

    float* ent_out = (float*)d_out;                   // [N_ENT*DIM] fp32
    float* usr_out = ent_out + (size_t)N_ENT * DIM;   // [N_USR*DIM] fp32

    // workspace layout (fp32)
    float* att   = (float*)d_ws;          // NE
    float* mseg  = att + NE;              // N_ENT
    float* sseg  = mseg + N_ENT;          // N_ENT
    int*   flags = (int*)(sseg + N_ENT);  // 2 ints

    detect_kernel<<<1, 64, 0, stream>>>(eidx, (const unsigned short*)ent, flags);

    // harness poisons d_out/d_ws with 0xAA — zero what we accumulate into
    hipMemsetAsync(d_out, 0, (size_t)(N_ENT + N_USR) * DIM * sizeof(float), stream);
    hipMemsetAsync(mseg, 0, (size_t)2 * N_ENT * sizeof(float), stream);

    edge_att_kernel<<<NE / 4, 256, 0, stream>>>(ent, eidx, etype, wgt, att, mseg, flags);
    edge_exp_kernel<<<(NE + 255) / 256, 256, 0, stream>>>(eidx, att, mseg, sseg, flags);
    edge_agg_kernel<<<NE / 4, 256, 0, stream>>>(ent, eidx, etype, wgt, att, sseg, ent_out, flags);
    spmm_kernel<<<NNZV / 4, 256, 0, stream>>>(ent, irow, icol, ival, usr_out, flags);
    user_final_kernel<<<(N_USR + 255) / 256, 256, 0, stream>>>(usr, wgt, usr_out, flags);
}

// Round 4
// 698.266 us; speedup vs baseline: 1.2896x; 1.2896x over previous
//
#include <hip/hip_runtime.h>
#include <hip/hip_bf16.h>

#define N_ENT 100000
#define N_USR 50000
#define DIM   64
#define NE    1000000
#define NNZV  1000000
#define NRELM1 31
#define NSEG  (N_ENT + N_USR)          // concat: [heads | user rows]
#define SCAN_B 1024
#define NB    ((NSEG + SCAN_B - 1) / SCAN_B)   // 147

__device__ __forceinline__ float bf2f(unsigned short u) {
    return __uint_as_float(((unsigned int)u) << 16);
}
__device__ __forceinline__ int geti(const int* p, size_t i, int is64) {
    return is64 ? p[2 * i] : p[i];     // int64 little-endian low word
}
__device__ __forceinline__ float getf(const void* p, size_t i, int isf32) {
    return isf32 ? ((const float*)p)[i] : bf2f(((const unsigned short*)p)[i]);
}
__device__ __forceinline__ int clampi(int v, int lo, int hi) {
    return v < lo ? lo : (v > hi ? hi : v);
}

// ---------------- dtype detection (deterministic, capture-safe) ----------------
__global__ void detect_kernel(const int* __restrict__ eidx,
                              const unsigned short* __restrict__ ent,
                              int* __restrict__ flags) {
    int lane = threadIdx.x & 63;
    int odd = eidx[2 * lane + 1];
    unsigned long long nz = __ballot(odd != 0);
    float v0 = fabsf(bf2f(ent[lane]));
    float v1 = fabsf(bf2f(ent[64 + lane]));
    int wild = (int)((v0 > 100.f) || (v0 != 0.f && v0 < 1e-10f)) +
               (int)((v1 > 100.f) || (v1 != 0.f && v1 < 1e-10f));
    #pragma unroll
    for (int off = 32; off >= 1; off >>= 1) wild += __shfl_xor(wild, off, 64);
    if (lane == 0) {
        flags[0] = (nz == 0ULL) ? 1 : 0;   // is64
        flags[1] = (wild >= 16) ? 1 : 0;   // isf32
    }
}

// ---------------- histogram: edge heads + interact rows into concat cnt ----------------
__global__ __launch_bounds__(256) void hist_kernel(
    const int* __restrict__ eidx, const int* __restrict__ irow,
    int* __restrict__ cnt, const int* __restrict__ flags)
{
    int t = blockIdx.x * blockDim.x + threadIdx.x;
    int is64 = flags[0];
    if (t < NE) {
        int head = clampi(geti(eidx, t, is64), 0, N_ENT - 1);
        atomicAdd(cnt + head, 1);
    } else if (t < NE + NNZV) {
        int row = clampi(geti(irow, t - NE, is64), 0, N_USR - 1);
        atomicAdd(cnt + N_ENT + row, 1);
    }
}

// ---------------- scan stage 1: per-block exclusive scan + block totals ----------------
__global__ __launch_bounds__(SCAN_B) void scan1_kernel(
    const int* __restrict__ cnt, int* __restrict__ loc, int* __restrict__ btot)
{
    __shared__ int tmp[SCAN_B];
    int i = blockIdx.x * SCAN_B + threadIdx.x;
    int v = (i < NSEG) ? cnt[i] : 0;
    tmp[threadIdx.x] = v;
    __syncthreads();
    for (int off = 1; off < SCAN_B; off <<= 1) {
        int t = (threadIdx.x >= off) ? tmp[threadIdx.x - off] : 0;
        __syncthreads();
        tmp[threadIdx.x] += t;
        __syncthreads();
    }
    if (i < NSEG) loc[i] = tmp[threadIdx.x] - v;          // exclusive
    if (threadIdx.x == SCAN_B - 1) btot[blockIdx.x] = tmp[SCAN_B - 1];
}

// ---------------- scan stage 2: scan the block totals (single block, LDS) ----------------
__global__ void scan2_kernel(int* __restrict__ btot) {
    __shared__ int t[NB];
    if (threadIdx.x < NB) t[threadIdx.x] = btot[threadIdx.x];
    __syncthreads();
    if (threadIdx.x == 0) {
        int s = 0;
        for (int i = 0; i < NB; ++i) { int x = t[i]; t[i] = s; s += x; }
    }
    __syncthreads();
    if (threadIdx.x < NB) btot[threadIdx.x] = t[threadIdx.x];
}

// ---------------- scan stage 3: materialize offsets + init cursors ----------------
__global__ __launch_bounds__(256) void offs_kernel(
    const int* __restrict__ loc, const int* __restrict__ btot,
    int* __restrict__ offs, int* __restrict__ cursor)
{
    int i = blockIdx.x * blockDim.x + threadIdx.x;
    if (i >= NSEG) return;
    int o = loc[i] + btot[i >> 10];
    offs[i] = o;
    cursor[i] = o;
}

// ---------------- scatter edges + nnz into CSR slots ----------------
__global__ __launch_bounds__(256) void scatter_kernel(
    const int* __restrict__ eidx, const int* __restrict__ etype,
    const int* __restrict__ irow, const int* __restrict__ icol,
    const void* __restrict__ ival,
    int* __restrict__ cursor,
    unsigned int* __restrict__ csr_e,   // [(tail<<5)|rel]
    unsigned int* __restrict__ col_s, float* __restrict__ val_s,
    const int* __restrict__ flags)
{
    int t = blockIdx.x * blockDim.x + threadIdx.x;
    int is64 = flags[0], isf32 = flags[1];
    if (t < NE) {
        int head = clampi(geti(eidx, t, is64), 0, N_ENT - 1);
        int tail = clampi(geti(eidx, (size_t)NE + t, is64), 0, N_ENT - 1);
        int rel  = clampi(geti(etype, t, is64) - 1, 0, NRELM1 - 1);
        int pos = atomicAdd(cursor + head, 1);
        csr_e[pos] = ((unsigned)tail << 5) | (unsigned)rel;
    } else if (t < NE + NNZV) {
        int n = t - NE;
        int row = clampi(geti(irow, n, is64), 0, N_USR - 1);
        int col = clampi(geti(icol, n, is64), 0, N_ENT - 1);
        int pos = atomicAdd(cursor + N_ENT + row, 1) - NE;
        col_s[pos] = (unsigned)col;
        val_s[pos] = getf(ival, n, isf32);
    }
}

// ---------------- entity aggregation: one wave per head, online softmax ----------------
__global__ __launch_bounds__(256) void agg_head_kernel(
    const void* __restrict__ ent, const void* __restrict__ wgt,
    const int* __restrict__ offs, const int* __restrict__ cnt,
    const unsigned int* __restrict__ csr_e,
    float* __restrict__ ent_out,        // [N_ENT,64] fp32 d_out (written, not accumulated)
    const int* __restrict__ flags)
{
    __shared__ float w[NRELM1][DIM];
    int isf32 = flags[1];
    for (int i = threadIdx.x; i < NRELM1 * DIM; i += blockDim.x)
        ((float*)w)[i] = getf(wgt, i, isf32);
    __syncthreads();

    int h = (blockIdx.x * blockDim.x + threadIdx.x) >> 6;
    int lane = threadIdx.x & 63;
    if (h >= N_ENT) return;
    int start = offs[h];
    int deg   = cnt[h];

    float hval = getf(ent, (size_t)h * DIM + lane, isf32);
    float m = 0.f, s = 0.f, acc = 0.f;   // att >= 0, so m=0 is a valid floor

    if (deg > 0) {
        unsigned pk = csr_e[start];
        for (int j = 0; j < deg; ++j) {
            unsigned pk_next = (j + 1 < deg) ? csr_e[start + j + 1] : 0u;
            int tail = (int)(pk >> 5);
            int rel  = (int)(pk & 31u);
            float rv = w[rel][lane];
            float tval = getf(ent, (size_t)tail * DIM + lane, isf32);
            float hr = hval * rv, tr = tval * rv;
            float hh = hr * hr, tt = tr * tr;
            #pragma unroll
            for (int off = 32; off >= 1; off >>= 1) {
                hh += __shfl_xor(hh, off, 64);
                tt += __shfl_xor(tt, off, 64);
            }
            float a = hh * tt;                    // (||h*r|| ||t*r||)^2
            float mn = fmaxf(m, a);
            float scale = __expf(m - mn);
            float ex = __expf(a - mn);
            s = s * scale + ex;
            acc = acc * scale + ex * (tval * rv);
            m = mn;
            pk = pk_next;
        }
    }
    ent_out[(size_t)h * DIM + lane] = (s > 0.f) ? acc / s : 0.f;
}

// ---------------- user spmm by row + fused softmax gate epilogue ----------------
__global__ __launch_bounds__(256) void spmm_row_kernel(
    const void* __restrict__ ent, const void* __restrict__ usr,
    const void* __restrict__ wgt,
    const int* __restrict__ offs, const int* __restrict__ cnt,
    const unsigned int* __restrict__ col_s, const float* __restrict__ val_s,
    float* __restrict__ usr_out,        // [N_USR,64] fp32
    const int* __restrict__ flags)
{
    __shared__ float w[NRELM1][DIM];
    int isf32 = flags[1];
    for (int i = threadIdx.x; i < NRELM1 * DIM; i += blockDim.x)
        ((float*)w)[i] = getf(wgt, i, isf32);
    __syncthreads();

    int u = (blockIdx.x * blockDim.x + threadIdx.x) >> 6;
    int lane = threadIdx.x & 63;
    if (u >= N_USR) return;
    int start = offs[N_ENT + u] - NE;
    int deg   = cnt[N_ENT + u];

    float acc = 0.f;
    if (deg > 0) {
        unsigned c = col_s[start];
        float v = val_s[start];
        for (int j = 0; j < deg; ++j) {
            unsigned c_next = 0u; float v_next = 0.f;
            if (j + 1 < deg) { c_next = col_s[start + j + 1]; v_next = val_s[start + j + 1]; }
            acc += v * getf(ent, (size_t)c * DIM + lane, isf32);
            c = c_next; v = v_next;
        }
    }

    // gate: out = ua + (softmax(ue @ W^T) @ W) * ua
    float ue = getf(usr, (size_t)u * DIM + lane, isf32);
    float p[NRELM1];
    float mx = -1e30f;
    #pragma unroll
    for (int r = 0; r < NRELM1; ++r) {
        float t = ue * w[r][lane];
        #pragma unroll
        for (int off = 32; off >= 1; off >>= 1) t += __shfl_xor(t, off, 64);
        p[r] = t;                      // all lanes hold full dot product
        mx = fmaxf(mx, t);
    }
    float sum = 0.f;
    #pragma unroll
    for (int r = 0; r < NRELM1; ++r) { p[r] = __expf(p[r] - mx); sum += p[r]; }
    float inv = 1.f / sum;
    float g = 0.f;
    #pragma unroll
    for (int r = 0; r < NRELM1; ++r) g += p[r] * w[r][lane];
    g *= inv;
    usr_out[(size_t)u * DIM + lane] = acc + g * acc;
}

extern "C" void kernel_launch(void* const* d_in, const int* in_sizes, int n_in,
                              void* d_out, int out_size, void* d_ws, size_t ws_size,
                              hipStream_t stream) {
    const void* ent  = d_in[0];
    const void* usr  = d_in[1];
    const int* eidx  = (const int*)d_in[2];
    const int* etype = (const int*)d_in[3];
    const int* irow  = (const int*)d_in[4];
    const int* icol  = (const int*)d_in[5];
    const void* ival = d_in[6];
    const void* wgt  = d_in[7];

    float* ent_out = (float*)d_out;                   // [N_ENT*DIM] fp32
    float* usr_out = ent_out + (size_t)N_ENT * DIM;   // [N_USR*DIM] fp32

    // workspace layout
    int* cnt    = (int*)d_ws;            // NSEG
    int* loc    = cnt + NSEG;            // NSEG
    int* btot   = loc + NSEG;            // NB (pad 256)
    int* offs   = btot + 256;            // NSEG
    int* cursor = offs + NSEG;           // NSEG
    int* flags  = cursor + NSEG;         // 2
    unsigned int* csr_e = (unsigned int*)(flags + 2);  // NE
    unsigned int* col_s = csr_e + NE;                  // NNZV
    float*        val_s = (float*)(col_s + NNZV);      // NNZV

    detect_kernel<<<1, 64, 0, stream>>>(eidx, (const unsigned short*)ent, flags);
    hipMemsetAsync(cnt, 0, (size_t)NSEG * sizeof(int), stream);

    hist_kernel<<<(NE + NNZV + 255) / 256, 256, 0, stream>>>(eidx, irow, cnt, flags);
    scan1_kernel<<<NB, SCAN_B, 0, stream>>>(cnt, loc, btot);
    scan2_kernel<<<1, 256, 0, stream>>>(btot);
    offs_kernel<<<(NSEG + 255) / 256, 256, 0, stream>>>(loc, btot, offs, cursor);
    scatter_kernel<<<(NE + NNZV + 255) / 256, 256, 0, stream>>>(
        eidx, etype, irow, icol, ival, cursor, csr_e, col_s, val_s, flags);
    agg_head_kernel<<<(N_ENT * DIM) / 256, 256, 0, stream>>>(
        ent, wgt, offs, cnt, csr_e, ent_out, flags);
    spmm_row_kernel<<<(N_USR * DIM) / 256, 256, 0, stream>>>(
        ent, usr, wgt, offs, cnt, col_s, val_s, usr_out, flags);
}